// Round 7
// baseline (217.304 us; speedup 1.0000x reference)
//
#include <hip/hip_runtime.h>

#define B 2
#define S 2048
#define H 768
#define NH 12
#define HD 64
#define BS (B * S)
#define LOG2E 1.4426950408889634f

typedef unsigned short u16;
typedef short short8 __attribute__((ext_vector_type(8)));
typedef float f32x4 __attribute__((ext_vector_type(4)));

// fp32 -> bf16 round-to-nearest-even
__device__ __forceinline__ u16 f2bf(float f) {
    union { float f; unsigned u; } c; c.f = f;
    unsigned u = c.u + 0x7FFFu + ((c.u >> 16) & 1u);
    return (u16)(u >> 16);
}
__device__ __forceinline__ float bf2f(u16 h) {
    union { unsigned u; float f; } c; c.u = ((unsigned)h) << 16;
    return c.f;
}

// async global->LDS DMA, 16 B per lane; lds dest = wave-uniform base + lane*16
__device__ __forceinline__ void g2l16(const u16* g, u16* l) {
    __builtin_amdgcn_global_load_lds(
        (const __attribute__((address_space(1))) void*)g,
        (__attribute__((address_space(3))) void*)l, 16, 0, 0);
}

// ---------------------------------------------------------------------------
// Prep 1: hidden_states fp32 -> bf16
// ---------------------------------------------------------------------------
__global__ __launch_bounds__(256) void prep_hs_kernel(
    const float* __restrict__ src, u16* __restrict__ dst)
{
    size_t i = ((size_t)blockIdx.x * 256 + threadIdx.x) * 8;
    float4 a = *(const float4*)(src + i);
    float4 b = *(const float4*)(src + i + 4);
    short8 p;
    p[0] = (short)f2bf(a.x); p[1] = (short)f2bf(a.y);
    p[2] = (short)f2bf(a.z); p[3] = (short)f2bf(a.w);
    p[4] = (short)f2bf(b.x); p[5] = (short)f2bf(b.y);
    p[6] = (short)f2bf(b.z); p[7] = (short)f2bf(b.w);
    *(short8*)(dst + i) = p;
}

// ---------------------------------------------------------------------------
// Prep 2: W [768,768] fp32 -> WT bf16 (WT[n][k] = W[k][n])
// ---------------------------------------------------------------------------
__global__ __launch_bounds__(256) void prep_w_kernel(
    const float* __restrict__ Wq, const float* __restrict__ Wk,
    const float* __restrict__ Wv, const float* __restrict__ Wo,
    u16* __restrict__ WTqkv, u16* __restrict__ WTo)
{
    __shared__ float Lt[64 * 65];
    const int t = threadIdx.x;
    const int z = blockIdx.z;
    const float* W = (z == 0) ? Wq : (z == 1) ? Wk : (z == 2) ? Wv : Wo;
    u16* D = (z == 3) ? WTo : (WTqkv + (size_t)z * H * H);
    const int k0 = blockIdx.x * 64, n0 = blockIdx.y * 64;

    #pragma unroll
    for (int u = 0; u < 4; ++u) {
        int f = t + u * 256;
        int r = f >> 4, c4 = (f & 15) * 4;
        float4 w = *(const float4*)(W + (size_t)(k0 + r) * H + n0 + c4);
        Lt[r * 65 + c4 + 0] = w.x; Lt[r * 65 + c4 + 1] = w.y;
        Lt[r * 65 + c4 + 2] = w.z; Lt[r * 65 + c4 + 3] = w.w;
    }
    __syncthreads();
    #pragma unroll
    for (int u = 0; u < 4; ++u) {
        int f = t + u * 256;
        int n = f >> 4, k4 = (f & 15) * 4;
        ushort4 p;
        p.x = f2bf(Lt[(k4 + 0) * 65 + n]);
        p.y = f2bf(Lt[(k4 + 1) * 65 + n]);
        p.z = f2bf(Lt[(k4 + 2) * 65 + n]);
        p.w = f2bf(Lt[(k4 + 3) * 65 + n]);
        *(ushort4*)(D + (size_t)(n0 + n) * H + k0 + k4) = p;
    }
}

// ---------------------------------------------------------------------------
// Fused QKV GEMM, bf16 MFMA. Register-prefetch software pipeline.
// ---------------------------------------------------------------------------
__global__ __launch_bounds__(256) void gemm_qkv_kernel(
    const u16* __restrict__ A, const u16* __restrict__ BT,
    const float* __restrict__ bq, const float* __restrict__ bk,
    const float* __restrict__ bv,
    u16* __restrict__ Qb, u16* __restrict__ Kb, u16* __restrict__ VT)
{
    __shared__ alignas(16) u16 As[128 * 72];
    __shared__ alignas(16) u16 Bs[128 * 72];

    const int tid  = threadIdx.x;
    const int w    = tid >> 6;
    const int lane = tid & 63;
    const int quad = lane >> 4;
    const int l15  = lane & 15;
    const int wm = (w & 1) * 64, wn = (w >> 1) * 64;
    const int m0 = blockIdx.x * 128;
    const int n0 = blockIdx.y * 128;
    const int lr = tid >> 3, lc8 = (tid & 7) * 8;

    f32x4 acc[4][4];
    #pragma unroll
    for (int i = 0; i < 4; ++i)
        #pragma unroll
        for (int j = 0; j < 4; ++j) acc[i][j] = (f32x4){0.f, 0.f, 0.f, 0.f};

    short8 pa[2], pb[2], pa2[2], pb2[2];
    #pragma unroll
    for (int u = 0; u < 2; ++u) {
        pa[u]  = *(const short8*)(A  + (size_t)(m0 + lr + u * 32) * H + lc8);
        pb[u]  = *(const short8*)(BT + (size_t)(n0 + lr + u * 32) * H + lc8);
        pa2[u] = *(const short8*)(A  + (size_t)(m0 + lr + 64 + u * 32) * H + lc8);
        pb2[u] = *(const short8*)(BT + (size_t)(n0 + lr + 64 + u * 32) * H + lc8);
    }

    for (int k0 = 0; k0 < H; k0 += 64) {
        __syncthreads();
        #pragma unroll
        for (int u = 0; u < 2; ++u) {
            *(short8*)&As[(lr + u * 32) * 72 + lc8] = pa[u];
            *(short8*)&Bs[(lr + u * 32) * 72 + lc8] = pb[u];
            *(short8*)&As[(lr + 64 + u * 32) * 72 + lc8] = pa2[u];
            *(short8*)&Bs[(lr + 64 + u * 32) * 72 + lc8] = pb2[u];
        }
        if (k0 + 64 < H) {
            #pragma unroll
            for (int u = 0; u < 2; ++u) {
                pa[u]  = *(const short8*)(A  + (size_t)(m0 + lr + u * 32) * H + k0 + 64 + lc8);
                pb[u]  = *(const short8*)(BT + (size_t)(n0 + lr + u * 32) * H + k0 + 64 + lc8);
                pa2[u] = *(const short8*)(A  + (size_t)(m0 + lr + 64 + u * 32) * H + k0 + 64 + lc8);
                pb2[u] = *(const short8*)(BT + (size_t)(n0 + lr + 64 + u * 32) * H + k0 + 64 + lc8);
            }
        }
        __syncthreads();
        #pragma unroll
        for (int kc = 0; kc < 64; kc += 32) {
            short8 af[4], bf[4];
            #pragma unroll
            for (int mi = 0; mi < 4; ++mi)
                af[mi] = *(const short8*)&As[(wm + mi * 16 + l15) * 72 + kc + quad * 8];
            #pragma unroll
            for (int ni = 0; ni < 4; ++ni)
                bf[ni] = *(const short8*)&Bs[(wn + ni * 16 + l15) * 72 + kc + quad * 8];
            #pragma unroll
            for (int mi = 0; mi < 4; ++mi)
                #pragma unroll
                for (int ni = 0; ni < 4; ++ni)
                    acc[mi][ni] = __builtin_amdgcn_mfma_f32_16x16x32_bf16(
                        af[mi], bf[ni], acc[mi][ni], 0, 0, 0);
        }
    }

    #pragma unroll
    for (int mi = 0; mi < 4; ++mi) {
        const int mbase = m0 + wm + mi * 16 + quad * 4;
        #pragma unroll
        for (int ni = 0; ni < 4; ++ni) {
            const int col = n0 + wn + ni * 16 + l15;      // 0..2303
            const int which = col / H;
            const int c = col - which * H;
            const int h = c >> 6, d = c & 63;
            if (which == 2) {
                const float bias = bv[c];
                const int b_ = mbase >> 11, s = mbase & (S - 1);
                ushort4 pk;
                pk.x = f2bf(acc[mi][ni][0] + bias);
                pk.y = f2bf(acc[mi][ni][1] + bias);
                pk.z = f2bf(acc[mi][ni][2] + bias);
                pk.w = f2bf(acc[mi][ni][3] + bias);
                *(ushort4*)&VT[(((size_t)b_ * NH + h) * HD + d) * S + s] = pk;
            } else {
                u16* dst = (which == 0) ? Qb : Kb;
                const float bias = (which == 0) ? bq[c] : bk[c];
                #pragma unroll
                for (int r = 0; r < 4; ++r) {
                    int m = mbase + r;
                    int b_ = m >> 11, s = m & (S - 1);
                    dst[(((size_t)b_ * NH + h) * S + s) * HD + d] =
                        f2bf(acc[mi][ni][r] + bias);
                }
            }
        }
    }
}

// ---------------------------------------------------------------------------
// Output projection: out[4096,768] fp32 = ctxb @ WTo^T + bo
// 128x64 tile (grid 32x12=384 blocks) to fix undersaturation at N=768.
// Wave tile 64x32 (mi 4, ni 2).
// ---------------------------------------------------------------------------
__global__ __launch_bounds__(256) void gemm_out_kernel(
    const u16* __restrict__ A, const u16* __restrict__ BT,
    const float* __restrict__ bo, float* __restrict__ out)
{
    __shared__ alignas(16) u16 As[128 * 72];
    __shared__ alignas(16) u16 Bs[64 * 72];

    const int tid  = threadIdx.x;
    const int w    = tid >> 6;
    const int lane = tid & 63;
    const int quad = lane >> 4;
    const int l15  = lane & 15;
    const int wm = (w & 1) * 64, wn = (w >> 1) * 32;
    const int m0 = blockIdx.x * 128;
    const int n0 = blockIdx.y * 64;
    const int lr = tid >> 3, lc8 = (tid & 7) * 8;

    f32x4 acc[4][2];
    #pragma unroll
    for (int i = 0; i < 4; ++i)
        #pragma unroll
        for (int j = 0; j < 2; ++j) acc[i][j] = (f32x4){0.f, 0.f, 0.f, 0.f};

    short8 pa[2], pa2[2], pb[2];
    #pragma unroll
    for (int u = 0; u < 2; ++u) {
        pa[u]  = *(const short8*)(A  + (size_t)(m0 + lr + u * 32) * H + lc8);
        pa2[u] = *(const short8*)(A  + (size_t)(m0 + lr + 64 + u * 32) * H + lc8);
        pb[u]  = *(const short8*)(BT + (size_t)(n0 + lr + u * 32) * H + lc8);
    }

    for (int k0 = 0; k0 < H; k0 += 64) {
        __syncthreads();
        #pragma unroll
        for (int u = 0; u < 2; ++u) {
            *(short8*)&As[(lr + u * 32) * 72 + lc8] = pa[u];
            *(short8*)&As[(lr + 64 + u * 32) * 72 + lc8] = pa2[u];
            *(short8*)&Bs[(lr + u * 32) * 72 + lc8] = pb[u];
        }
        if (k0 + 64 < H) {
            #pragma unroll
            for (int u = 0; u < 2; ++u) {
                pa[u]  = *(const short8*)(A  + (size_t)(m0 + lr + u * 32) * H + k0 + 64 + lc8);
                pa2[u] = *(const short8*)(A  + (size_t)(m0 + lr + 64 + u * 32) * H + k0 + 64 + lc8);
                pb[u]  = *(const short8*)(BT + (size_t)(n0 + lr + u * 32) * H + k0 + 64 + lc8);
            }
        }
        __syncthreads();
        #pragma unroll
        for (int kc = 0; kc < 64; kc += 32) {
            short8 af[4], bf[2];
            #pragma unroll
            for (int mi = 0; mi < 4; ++mi)
                af[mi] = *(const short8*)&As[(wm + mi * 16 + l15) * 72 + kc + quad * 8];
            #pragma unroll
            for (int ni = 0; ni < 2; ++ni)
                bf[ni] = *(const short8*)&Bs[(wn + ni * 16 + l15) * 72 + kc + quad * 8];
            #pragma unroll
            for (int mi = 0; mi < 4; ++mi)
                #pragma unroll
                for (int ni = 0; ni < 2; ++ni)
                    acc[mi][ni] = __builtin_amdgcn_mfma_f32_16x16x32_bf16(
                        af[mi], bf[ni], acc[mi][ni], 0, 0, 0);
        }
    }

    #pragma unroll
    for (int mi = 0; mi < 4; ++mi) {
        const int mbase = m0 + wm + mi * 16 + quad * 4;
        #pragma unroll
        for (int ni = 0; ni < 2; ++ni) {
            const int col = n0 + wn + ni * 16 + l15;
            const float bias = bo[col];
            #pragma unroll
            for (int r = 0; r < 4; ++r)
                out[(size_t)(mbase + r) * H + col] = acc[mi][ni][r] + bias;
        }
    }
}

// ---------------------------------------------------------------------------
// RoPE (reference quirk: tables indexed by HEAD), bf16 in-place.
// Q additionally scaled by (1/sqrt(HD)) * log2(e) so scores are exp2-ready.
// ---------------------------------------------------------------------------
__global__ __launch_bounds__(256) void rope_kernel(
    u16* __restrict__ Qb, u16* __restrict__ Kb,
    const float* __restrict__ cosp, const float* __restrict__ sinp)
{
    int row  = blockIdx.x * 4 + (threadIdx.x >> 6);
    int lane = threadIdx.x & 63;
    u16* X = (blockIdx.y == 0) ? Qb : Kb;
    const float scale = (blockIdx.y == 0) ? (0.125f * LOG2E) : 1.0f;
    int n = (row / S) % NH;
    float x = bf2f(X[(size_t)row * HD + lane]);
    int p = (lane < 32) ? (2 * lane + 1) : (2 * (lane - 32));
    float xp = __shfl(x, p, 64);
    float x2 = (lane < 32) ? -xp : xp;
    float c  = cosp[n * HD + lane];
    float sn = sinp[n * HD + lane];
    X[(size_t)row * HD + lane] = f2bf(fmaf(x, c, x2 * sn) * scale);
}

// ---------------------------------------------------------------------------
// Flash attention, bf16 MFMA, exp2 no-max softmax, DMA-double-buffered K/V
// (round-6 structure). NEW: 128-thread blocks, each wave owns 32 Q-rows as
// two 16-row strips -> K/V LDS fragments are read ONCE per wave and reused
// by both strips (halves DS traffic per FLOP); grid stays 768 blocks = 3/CU.
// ---------------------------------------------------------------------------
__global__ __launch_bounds__(128) void attn_mfma_kernel(
    const u16* __restrict__ Q, const u16* __restrict__ K,
    const u16* __restrict__ VT, const float* __restrict__ mask,
    u16* __restrict__ ctx)
{
    __shared__ alignas(16) u16 Kbuf[2][64 * 64];  // [key][dim], swizzled
    __shared__ alignas(16) u16 Vbuf[2][64 * 64];  // [dim][key], swizzled
    __shared__ alignas(16) u16 Ps[2 * 32 * 72];   // per-wave [qrow(32)][key]
    __shared__ float mt[S];                       // (1-mask)*(-1e4)*log2e

    const int tid  = threadIdx.x;                 // 0..127
    const int w    = tid >> 6;                    // wave 0..1
    const int lane = tid & 63;
    const int quad = lane >> 4;
    const int l15  = lane & 15;
    const int bn = blockIdx.y, b = bn / NH, hh = bn % NH;
    const int q0 = blockIdx.x * 64;
    const int NT = S / 64;

    // mask row -> LDS once (2048 floats, 128 threads x 4 x float4)
    {
        const float* mb = mask + (size_t)b * S;
        #pragma unroll
        for (int u = 0; u < 4; ++u) {
            int j = (u * 128 + tid) * 4;
            float4 mv = *(const float4*)(mb + j);
            mt[j + 0] = (1.0f - mv.x) * (-10000.0f * LOG2E);
            mt[j + 1] = (1.0f - mv.y) * (-10000.0f * LOG2E);
            mt[j + 2] = (1.0f - mv.z) * (-10000.0f * LOG2E);
            mt[j + 3] = (1.0f - mv.w) * (-10000.0f * LOG2E);
        }
    }

    // Q A-fragments for both strips (wave rows w*32 + t*16 + l15)
    short8 qa[2][2];
    #pragma unroll
    for (int t = 0; t < 2; ++t) {
        const u16* Qp =
            Q + ((size_t)bn * S + q0 + w * 32 + t * 16 + l15) * HD + quad * 8;
        qa[t][0] = *(const short8*)(Qp);
        qa[t][1] = *(const short8*)(Qp + 32);
    }

    const u16* Kb = K + (size_t)bn * S * HD;
    const u16* Vb = VT + (size_t)bn * HD * S;

    // staging: slot s = u*128+tid; row = s>>3, phys chunk = (s&7)^(row&7)
    int srow[4], slc[4];
    #pragma unroll
    for (int u = 0; u < 4; ++u) {
        int s = u * 128 + tid;
        srow[u] = s >> 3;
        slc[u]  = (s & 7) ^ (srow[u] & 7);
    }

    #define STAGE(JT, NB)                                                     \
        _Pragma("unroll")                                                     \
        for (int u = 0; u < 4; ++u) {                                         \
            g2l16(Kb + (size_t)((JT) * 64 + srow[u]) * HD + slc[u] * 8,       \
                  &Kbuf[NB][(u * 128 + w * 64) * 8]);                         \
            g2l16(Vb + (size_t)srow[u] * S + (JT) * 64 + slc[u] * 8,          \
                  &Vbuf[NB][(u * 128 + w * 64) * 8]);                         \
        }

    STAGE(0, 0)

    f32x4 o[2][4];
    float l_p[2][4];
    #pragma unroll
    for (int t = 0; t < 2; ++t)
        #pragma unroll
        for (int n = 0; n < 4; ++n) {
            o[t][n] = (f32x4){0.f, 0.f, 0.f, 0.f};
            l_p[t][n] = 0.f;
        }

    for (int jt = 0; jt < NT; ++jt) {
        const int cur = jt & 1;
        __syncthreads();               // drains own DMA (vmcnt 0) + syncs all
        if (jt + 1 < NT) { STAGE(jt + 1, cur ^ 1) }   // overlaps compute below

        const u16* Kc = Kbuf[cur];
        const u16* Vc = Vbuf[cur];

        // QK^T for both strips; K fragments read once
        f32x4 sc[2][4];
        #pragma unroll
        for (int n = 0; n < 4; ++n) {
            const int row = n * 16 + l15, sw = row & 7;
            const short8 kb0 = *(const short8*)&Kc[row * 64 + ((quad) ^ sw) * 8];
            const short8 kb1 = *(const short8*)&Kc[row * 64 + ((quad + 4) ^ sw) * 8];
            #pragma unroll
            for (int t = 0; t < 2; ++t) {
                f32x4 a = (f32x4){0.f, 0.f, 0.f, 0.f};
                a = __builtin_amdgcn_mfma_f32_16x16x32_bf16(qa[t][0], kb0, a, 0, 0, 0);
                a = __builtin_amdgcn_mfma_f32_16x16x32_bf16(qa[t][1], kb1, a, 0, 0, 0);
                sc[t][n] = a;
            }
        }

        // V fragments issued early (once per wave), consumed after softmax
        short8 vf[4][2];
        #pragma unroll
        for (int n = 0; n < 4; ++n) {
            const int row = n * 16 + l15, sw = row & 7;
            vf[n][0] = *(const short8*)&Vc[row * 64 + ((quad) ^ sw) * 8];
            vf[n][1] = *(const short8*)&Vc[row * 64 + ((quad + 4) ^ sw) * 8];
        }

        // unnormalized softmax: p = exp2(s + mt)
        #pragma unroll
        for (int n = 0; n < 4; ++n) {
            const float mtn = mt[jt * 64 + n * 16 + l15];
            #pragma unroll
            for (int t = 0; t < 2; ++t)
                #pragma unroll
                for (int r = 0; r < 4; ++r) {
                    float p = __builtin_amdgcn_exp2f(sc[t][n][r] + mtn);
                    l_p[t][r] += p;
                    Ps[w * 2304 + (t * 16 + quad * 4 + r) * 72 + n * 16 + l15] =
                        f2bf(p);
                }
        }

        // wave-private LDS RAW ordering
        asm volatile("s_waitcnt lgkmcnt(0)" ::: "memory");

        short8 pa[2][2];
        #pragma unroll
        for (int t = 0; t < 2; ++t) {
            const u16* Pw = &Ps[w * 2304 + (t * 16 + l15) * 72 + quad * 8];
            pa[t][0] = *(const short8*)(Pw);
            pa[t][1] = *(const short8*)(Pw + 32);
        }
        #pragma unroll
        for (int n = 0; n < 4; ++n)
            #pragma unroll
            for (int t = 0; t < 2; ++t) {
                o[t][n] = __builtin_amdgcn_mfma_f32_16x16x32_bf16(
                    pa[t][0], vf[n][0], o[t][n], 0, 0, 0);
                o[t][n] = __builtin_amdgcn_mfma_f32_16x16x32_bf16(
                    pa[t][1], vf[n][1], o[t][n], 0, 0, 0);
            }
    }
    #undef STAGE

    // one-time row-sum reduction across the quad's 16 lanes, then store
    #pragma unroll
    for (int t = 0; t < 2; ++t)
        #pragma unroll
        for (int r = 0; r < 4; ++r) {
            float l = l_p[t][r];
            #pragma unroll
            for (int off = 8; off >= 1; off >>= 1)
                l += __shfl_xor(l, off, 16);
            float inv = 1.0f / l;
            int s = q0 + w * 32 + t * 16 + quad * 4 + r;
            #pragma unroll
            for (int n = 0; n < 4; ++n)
                ctx[((size_t)b * S + s) * H + hh * 64 + n * 16 + l15] =
                    f2bf(o[t][n][r] * inv);
        }
}

// ---------------------------------------------------------------------------
extern "C" void kernel_launch(void* const* d_in, const int* in_sizes, int n_in,
                              void* d_out, int out_size, void* d_ws, size_t ws_size,
                              hipStream_t stream)
{
    const float* hs   = (const float*)d_in[0];
    const float* mask = (const float*)d_in[1];
    const float* Wq   = (const float*)d_in[2];
    const float* bq   = (const float*)d_in[3];
    const float* Wk   = (const float*)d_in[4];
    const float* bk   = (const float*)d_in[5];
    const float* Wv   = (const float*)d_in[6];
    const float* bv   = (const float*)d_in[7];
    const float* Wo   = (const float*)d_in[8];
    const float* bo   = (const float*)d_in[9];
    const float* cosp = (const float*)d_in[10];
    const float* sinp = (const float*)d_in[11];
    float* out = (float*)d_out;

    const size_t per = (size_t)B * NH * S * HD;   // 3,145,728
    u16* ws    = (u16*)d_ws;
    u16* hsb   = ws;                              // bf16 hidden  [BS,H]
    u16* WTqkv = hsb + per;                       // bf16 [2304,768]
    u16* WTo   = WTqkv + (size_t)3 * H * H;       // bf16 [768,768]
    u16* Qb    = WTo + (size_t)H * H;             // bf16 [B,NH,S,HD]
    u16* Kb    = Qb + per;
    u16* VT    = Kb + per;                        // bf16 [B,NH,HD,S]
    u16* ctxb  = VT + per;                        // bf16 [BS,H]

    prep_hs_kernel<<<(BS * H) / 2048, 256, 0, stream>>>(hs, hsb);
    prep_w_kernel<<<dim3(12, 12, 4), 256, 0, stream>>>(
        Wq, Wk, Wv, Wo, WTqkv, WTo);

    gemm_qkv_kernel<<<dim3(BS / 128, 2304 / 128), 256, 0, stream>>>(
        hsb, WTqkv, bq, bk, bv, Qb, Kb, VT);

    rope_kernel<<<dim3(B * NH * S / 4, 2), 256, 0, stream>>>(
        Qb, Kb, cosp, sinp);

    attn_mfma_kernel<<<dim3(S / 64, B * NH), 128, 0, stream>>>(
        Qb, Kb, VT, mask, ctxb);

    gemm_out_kernel<<<dim3(BS / 128, H / 64), 256, 0, stream>>>(
        ctxb, WTo, bo, out);
}

// Round 8
// 200.940 us; speedup vs baseline: 1.0814x; 1.0814x over previous
//
#include <hip/hip_runtime.h>

#define B 2
#define S 2048
#define H 768
#define NH 12
#define HD 64
#define BS (B * S)
#define LOG2E 1.4426950408889634f

typedef unsigned short u16;
typedef short short8 __attribute__((ext_vector_type(8)));
typedef float f32x4 __attribute__((ext_vector_type(4)));
typedef float f32x16 __attribute__((ext_vector_type(16)));

// fp32 -> bf16 round-to-nearest-even
__device__ __forceinline__ u16 f2bf(float f) {
    union { float f; unsigned u; } c; c.f = f;
    unsigned u = c.u + 0x7FFFu + ((c.u >> 16) & 1u);
    return (u16)(u >> 16);
}
__device__ __forceinline__ float bf2f(u16 h) {
    union { unsigned u; float f; } c; c.u = ((unsigned)h) << 16;
    return c.f;
}
__device__ __forceinline__ f32x16 zero16() {
    f32x16 v;
    #pragma unroll
    for (int i = 0; i < 16; ++i) v[i] = 0.f;
    return v;
}

// async global->LDS DMA, 16 B per lane; lds dest = wave-uniform base + lane*16
__device__ __forceinline__ void g2l16(const u16* g, u16* l) {
    __builtin_amdgcn_global_load_lds(
        (const __attribute__((address_space(1))) void*)g,
        (__attribute__((address_space(3))) void*)l, 16, 0, 0);
}

// ---------------------------------------------------------------------------
// Prep 1: hidden_states fp32 -> bf16
// ---------------------------------------------------------------------------
__global__ __launch_bounds__(256) void prep_hs_kernel(
    const float* __restrict__ src, u16* __restrict__ dst)
{
    size_t i = ((size_t)blockIdx.x * 256 + threadIdx.x) * 8;
    float4 a = *(const float4*)(src + i);
    float4 b = *(const float4*)(src + i + 4);
    short8 p;
    p[0] = (short)f2bf(a.x); p[1] = (short)f2bf(a.y);
    p[2] = (short)f2bf(a.z); p[3] = (short)f2bf(a.w);
    p[4] = (short)f2bf(b.x); p[5] = (short)f2bf(b.y);
    p[6] = (short)f2bf(b.z); p[7] = (short)f2bf(b.w);
    *(short8*)(dst + i) = p;
}

// ---------------------------------------------------------------------------
// Prep 2: W [768,768] fp32 -> WT bf16 (WT[n][k] = W[k][n])
// ---------------------------------------------------------------------------
__global__ __launch_bounds__(256) void prep_w_kernel(
    const float* __restrict__ Wq, const float* __restrict__ Wk,
    const float* __restrict__ Wv, const float* __restrict__ Wo,
    u16* __restrict__ WTqkv, u16* __restrict__ WTo)
{
    __shared__ float Lt[64 * 65];
    const int t = threadIdx.x;
    const int z = blockIdx.z;
    const float* W = (z == 0) ? Wq : (z == 1) ? Wk : (z == 2) ? Wv : Wo;
    u16* D = (z == 3) ? WTo : (WTqkv + (size_t)z * H * H);
    const int k0 = blockIdx.x * 64, n0 = blockIdx.y * 64;

    #pragma unroll
    for (int u = 0; u < 4; ++u) {
        int f = t + u * 256;
        int r = f >> 4, c4 = (f & 15) * 4;
        float4 w = *(const float4*)(W + (size_t)(k0 + r) * H + n0 + c4);
        Lt[r * 65 + c4 + 0] = w.x; Lt[r * 65 + c4 + 1] = w.y;
        Lt[r * 65 + c4 + 2] = w.z; Lt[r * 65 + c4 + 3] = w.w;
    }
    __syncthreads();
    #pragma unroll
    for (int u = 0; u < 4; ++u) {
        int f = t + u * 256;
        int n = f >> 4, k4 = (f & 15) * 4;
        ushort4 p;
        p.x = f2bf(Lt[(k4 + 0) * 65 + n]);
        p.y = f2bf(Lt[(k4 + 1) * 65 + n]);
        p.z = f2bf(Lt[(k4 + 2) * 65 + n]);
        p.w = f2bf(Lt[(k4 + 3) * 65 + n]);
        *(ushort4*)(D + (size_t)(n0 + n) * H + k0 + k4) = p;
    }
}

// ---------------------------------------------------------------------------
// Fused QKV GEMM, bf16 MFMA. Register-prefetch software pipeline.
// ---------------------------------------------------------------------------
__global__ __launch_bounds__(256) void gemm_qkv_kernel(
    const u16* __restrict__ A, const u16* __restrict__ BT,
    const float* __restrict__ bq, const float* __restrict__ bk,
    const float* __restrict__ bv,
    u16* __restrict__ Qb, u16* __restrict__ Kb, u16* __restrict__ VT)
{
    __shared__ alignas(16) u16 As[128 * 72];
    __shared__ alignas(16) u16 Bs[128 * 72];

    const int tid  = threadIdx.x;
    const int w    = tid >> 6;
    const int lane = tid & 63;
    const int quad = lane >> 4;
    const int l15  = lane & 15;
    const int wm = (w & 1) * 64, wn = (w >> 1) * 64;
    const int m0 = blockIdx.x * 128;
    const int n0 = blockIdx.y * 128;
    const int lr = tid >> 3, lc8 = (tid & 7) * 8;

    f32x4 acc[4][4];
    #pragma unroll
    for (int i = 0; i < 4; ++i)
        #pragma unroll
        for (int j = 0; j < 4; ++j) acc[i][j] = (f32x4){0.f, 0.f, 0.f, 0.f};

    short8 pa[2], pb[2], pa2[2], pb2[2];
    #pragma unroll
    for (int u = 0; u < 2; ++u) {
        pa[u]  = *(const short8*)(A  + (size_t)(m0 + lr + u * 32) * H + lc8);
        pb[u]  = *(const short8*)(BT + (size_t)(n0 + lr + u * 32) * H + lc8);
        pa2[u] = *(const short8*)(A  + (size_t)(m0 + lr + 64 + u * 32) * H + lc8);
        pb2[u] = *(const short8*)(BT + (size_t)(n0 + lr + 64 + u * 32) * H + lc8);
    }

    for (int k0 = 0; k0 < H; k0 += 64) {
        __syncthreads();
        #pragma unroll
        for (int u = 0; u < 2; ++u) {
            *(short8*)&As[(lr + u * 32) * 72 + lc8] = pa[u];
            *(short8*)&Bs[(lr + u * 32) * 72 + lc8] = pb[u];
            *(short8*)&As[(lr + 64 + u * 32) * 72 + lc8] = pa2[u];
            *(short8*)&Bs[(lr + 64 + u * 32) * 72 + lc8] = pb2[u];
        }
        if (k0 + 64 < H) {
            #pragma unroll
            for (int u = 0; u < 2; ++u) {
                pa[u]  = *(const short8*)(A  + (size_t)(m0 + lr + u * 32) * H + k0 + 64 + lc8);
                pb[u]  = *(const short8*)(BT + (size_t)(n0 + lr + u * 32) * H + k0 + 64 + lc8);
                pa2[u] = *(const short8*)(A  + (size_t)(m0 + lr + 64 + u * 32) * H + k0 + 64 + lc8);
                pb2[u] = *(const short8*)(BT + (size_t)(n0 + lr + 64 + u * 32) * H + k0 + 64 + lc8);
            }
        }
        __syncthreads();
        #pragma unroll
        for (int kc = 0; kc < 64; kc += 32) {
            short8 af[4], bf[4];
            #pragma unroll
            for (int mi = 0; mi < 4; ++mi)
                af[mi] = *(const short8*)&As[(wm + mi * 16 + l15) * 72 + kc + quad * 8];
            #pragma unroll
            for (int ni = 0; ni < 4; ++ni)
                bf[ni] = *(const short8*)&Bs[(wn + ni * 16 + l15) * 72 + kc + quad * 8];
            #pragma unroll
            for (int mi = 0; mi < 4; ++mi)
                #pragma unroll
                for (int ni = 0; ni < 4; ++ni)
                    acc[mi][ni] = __builtin_amdgcn_mfma_f32_16x16x32_bf16(
                        af[mi], bf[ni], acc[mi][ni], 0, 0, 0);
        }
    }

    #pragma unroll
    for (int mi = 0; mi < 4; ++mi) {
        const int mbase = m0 + wm + mi * 16 + quad * 4;
        #pragma unroll
        for (int ni = 0; ni < 4; ++ni) {
            const int col = n0 + wn + ni * 16 + l15;      // 0..2303
            const int which = col / H;
            const int c = col - which * H;
            const int h = c >> 6, d = c & 63;
            if (which == 2) {
                const float bias = bv[c];
                const int b_ = mbase >> 11, s = mbase & (S - 1);
                ushort4 pk;
                pk.x = f2bf(acc[mi][ni][0] + bias);
                pk.y = f2bf(acc[mi][ni][1] + bias);
                pk.z = f2bf(acc[mi][ni][2] + bias);
                pk.w = f2bf(acc[mi][ni][3] + bias);
                *(ushort4*)&VT[(((size_t)b_ * NH + h) * HD + d) * S + s] = pk;
            } else {
                u16* dst = (which == 0) ? Qb : Kb;
                const float bias = (which == 0) ? bq[c] : bk[c];
                #pragma unroll
                for (int r = 0; r < 4; ++r) {
                    int m = mbase + r;
                    int b_ = m >> 11, s = m & (S - 1);
                    dst[(((size_t)b_ * NH + h) * S + s) * HD + d] =
                        f2bf(acc[mi][ni][r] + bias);
                }
            }
        }
    }
}

// ---------------------------------------------------------------------------
// Output projection: out[4096,768] fp32 = ctxb @ WTo^T + bo  (128x64 tile)
// ---------------------------------------------------------------------------
__global__ __launch_bounds__(256) void gemm_out_kernel(
    const u16* __restrict__ A, const u16* __restrict__ BT,
    const float* __restrict__ bo, float* __restrict__ out)
{
    __shared__ alignas(16) u16 As[128 * 72];
    __shared__ alignas(16) u16 Bs[64 * 72];

    const int tid  = threadIdx.x;
    const int w    = tid >> 6;
    const int lane = tid & 63;
    const int quad = lane >> 4;
    const int l15  = lane & 15;
    const int wm = (w & 1) * 64, wn = (w >> 1) * 32;
    const int m0 = blockIdx.x * 128;
    const int n0 = blockIdx.y * 64;
    const int lr = tid >> 3, lc8 = (tid & 7) * 8;

    f32x4 acc[4][2];
    #pragma unroll
    for (int i = 0; i < 4; ++i)
        #pragma unroll
        for (int j = 0; j < 2; ++j) acc[i][j] = (f32x4){0.f, 0.f, 0.f, 0.f};

    short8 pa[2], pa2[2], pb[2];
    #pragma unroll
    for (int u = 0; u < 2; ++u) {
        pa[u]  = *(const short8*)(A  + (size_t)(m0 + lr + u * 32) * H + lc8);
        pa2[u] = *(const short8*)(A  + (size_t)(m0 + lr + 64 + u * 32) * H + lc8);
        pb[u]  = *(const short8*)(BT + (size_t)(n0 + lr + u * 32) * H + lc8);
    }

    for (int k0 = 0; k0 < H; k0 += 64) {
        __syncthreads();
        #pragma unroll
        for (int u = 0; u < 2; ++u) {
            *(short8*)&As[(lr + u * 32) * 72 + lc8] = pa[u];
            *(short8*)&As[(lr + 64 + u * 32) * 72 + lc8] = pa2[u];
            *(short8*)&Bs[(lr + u * 32) * 72 + lc8] = pb[u];
        }
        if (k0 + 64 < H) {
            #pragma unroll
            for (int u = 0; u < 2; ++u) {
                pa[u]  = *(const short8*)(A  + (size_t)(m0 + lr + u * 32) * H + k0 + 64 + lc8);
                pa2[u] = *(const short8*)(A  + (size_t)(m0 + lr + 64 + u * 32) * H + k0 + 64 + lc8);
                pb[u]  = *(const short8*)(BT + (size_t)(n0 + lr + u * 32) * H + k0 + 64 + lc8);
            }
        }
        __syncthreads();
        #pragma unroll
        for (int kc = 0; kc < 64; kc += 32) {
            short8 af[4], bf[2];
            #pragma unroll
            for (int mi = 0; mi < 4; ++mi)
                af[mi] = *(const short8*)&As[(wm + mi * 16 + l15) * 72 + kc + quad * 8];
            #pragma unroll
            for (int ni = 0; ni < 2; ++ni)
                bf[ni] = *(const short8*)&Bs[(wn + ni * 16 + l15) * 72 + kc + quad * 8];
            #pragma unroll
            for (int mi = 0; mi < 4; ++mi)
                #pragma unroll
                for (int ni = 0; ni < 2; ++ni)
                    acc[mi][ni] = __builtin_amdgcn_mfma_f32_16x16x32_bf16(
                        af[mi], bf[ni], acc[mi][ni], 0, 0, 0);
        }
    }

    #pragma unroll
    for (int mi = 0; mi < 4; ++mi) {
        const int mbase = m0 + wm + mi * 16 + quad * 4;
        #pragma unroll
        for (int ni = 0; ni < 2; ++ni) {
            const int col = n0 + wn + ni * 16 + l15;
            const float bias = bo[col];
            #pragma unroll
            for (int r = 0; r < 4; ++r)
                out[(size_t)(mbase + r) * H + col] = acc[mi][ni][r] + bias;
        }
    }
}

// ---------------------------------------------------------------------------
// RoPE (reference quirk: tables indexed by HEAD), bf16 in-place.
// Q additionally scaled by (1/sqrt(HD)) * log2(e) so scores are exp2-ready.
// ---------------------------------------------------------------------------
__global__ __launch_bounds__(256) void rope_kernel(
    u16* __restrict__ Qb, u16* __restrict__ Kb,
    const float* __restrict__ cosp, const float* __restrict__ sinp)
{
    int row  = blockIdx.x * 4 + (threadIdx.x >> 6);
    int lane = threadIdx.x & 63;
    u16* X = (blockIdx.y == 0) ? Qb : Kb;
    const float scale = (blockIdx.y == 0) ? (0.125f * LOG2E) : 1.0f;
    int n = (row / S) % NH;
    float x = bf2f(X[(size_t)row * HD + lane]);
    int p = (lane < 32) ? (2 * lane + 1) : (2 * (lane - 32));
    float xp = __shfl(x, p, 64);
    float x2 = (lane < 32) ? -xp : xp;
    float c  = cosp[n * HD + lane];
    float sn = sinp[n * HD + lane];
    X[(size_t)row * HD + lane] = f2bf(fmaf(x, c, x2 * sn) * scale);
}

// ---------------------------------------------------------------------------
// Flash attention, bf16 32x32x16 MFMA, exp2 no-max softmax, DMA-dbuf K/V
// (round-6 staging). 256 threads / 64 Q-rows / 768 blocks (keeps 12 waves/CU)
// but waves split 2 row-halves x 2 KEY-halves: each wave = 32 rows x 32 keys
// -> K/V/P DS ops per wave drop ~1.45x vs round 6. Each wave accumulates
// partial O and l over its key-half; one post-loop LDS combine (staging
// buffers reused) merges pairs. Mask term = 1 global dword/lane/jt (no mt LDS).
// ---------------------------------------------------------------------------
__global__ __launch_bounds__(256) void attn_mfma_kernel(
    const u16* __restrict__ Q, const u16* __restrict__ K,
    const u16* __restrict__ VT, const float* __restrict__ mask,
    u16* __restrict__ ctx)
{
    // smem: Kbuf 2x4096 u16 | Vbuf 2x4096 | Ps 4 waves x 32x40
    __shared__ alignas(16) u16 smem[21504];
    u16* const Kbase = smem;
    u16* const Vbase = smem + 8192;
    u16* const Psw   = smem + 16384 + (threadIdx.x >> 6) * 1280;

    const int tid  = threadIdx.x;
    const int w    = tid >> 6;
    const int lane = tid & 63;
    const int l31  = lane & 31;
    const int h5   = lane >> 5;
    const int rh   = w & 1;   // row-half
    const int kh   = w >> 1;  // key-half
    const int bn = blockIdx.y, b = bn / NH, hh = bn % NH;
    const int q0 = blockIdx.x * 64;
    const int NT = S / 64;

    // Q A-fragments (32x32x16): row = l31, k = kc*16 + h5*8 + j
    short8 qa[4];
    {
        const u16* Qp = Q + ((size_t)bn * S + q0 + rh * 32 + l31) * HD + h5 * 8;
        #pragma unroll
        for (int kc = 0; kc < 4; ++kc)
            qa[kc] = *(const short8*)(Qp + kc * 16);
    }

    const u16* Kg = K + (size_t)bn * S * HD;
    const u16* Vg = VT + (size_t)bn * HD * S;
    const float* mrow = mask + (size_t)b * S;

    int srow[2], slc[2];
    #pragma unroll
    for (int u = 0; u < 2; ++u) {
        int s = u * 256 + tid;
        srow[u] = s >> 3;
        slc[u]  = (s & 7) ^ (srow[u] & 7);
    }

    #define STAGE(JT, NB)                                                     \
        _Pragma("unroll")                                                     \
        for (int u = 0; u < 2; ++u) {                                         \
            g2l16(Kg + (size_t)((JT) * 64 + srow[u]) * HD + slc[u] * 8,       \
                  Kbase + (NB) * 4096 + (u * 256 + w * 64) * 8);              \
            g2l16(Vg + (size_t)srow[u] * S + (JT) * 64 + slc[u] * 8,          \
                  Vbase + (NB) * 4096 + (u * 256 + w * 64) * 8);              \
        }

    STAGE(0, 0)

    f32x16 o0 = zero16(), o1 = zero16();
    float l_p[16];
    #pragma unroll
    for (int i = 0; i < 16; ++i) l_p[i] = 0.f;

    for (int jt = 0; jt < NT; ++jt) {
        const int cur = jt & 1;
        const float mv = mrow[jt * 64 + kh * 32 + l31];  // L2-hot, 1 dword
        __syncthreads();               // drains own DMA + syncs all
        if (jt + 1 < NT) { STAGE(jt + 1, cur ^ 1) }

        const u16* Kc = Kbase + cur * 4096;
        const u16* Vc = Vbase + cur * 4096;

        // QK^T: 32 rows x 32 keys, dim 64 as 4 chunks of 16
        f32x16 sc = zero16();
        {
            const int krow = kh * 32 + l31;
            const int sw = krow & 7;
            #pragma unroll
            for (int kc = 0; kc < 4; ++kc) {
                const short8 kb =
                    *(const short8*)&Kc[krow * 64 + ((kc * 2 + h5) ^ sw) * 8];
                sc = __builtin_amdgcn_mfma_f32_32x32x16_bf16(qa[kc], kb, sc, 0, 0, 0);
            }
        }

        const float mt = (1.0f - mv) * (-10000.0f * LOG2E);
        #pragma unroll
        for (int reg = 0; reg < 16; ++reg) {
            float p = __builtin_amdgcn_exp2f(sc[reg] + mt);
            l_p[reg] += p;
            const int r32 = (reg & 3) + 8 * (reg >> 2) + 4 * h5;
            Psw[r32 * 40 + l31] = f2bf(p);
        }

        // wave-private LDS RAW ordering
        asm volatile("s_waitcnt lgkmcnt(0)" ::: "memory");

        // P A-frags: row = l31 (qrow), k = kc2*16 + h5*8 + j (key-local)
        const short8 pa0 = *(const short8*)&Psw[l31 * 40 + h5 * 8];
        const short8 pa1 = *(const short8*)&Psw[l31 * 40 + 16 + h5 * 8];

        // PV: V B-frags row = dim, key-in-tile = kh*32 + kc2*16 + h5*8
        #pragma unroll
        for (int nt = 0; nt < 2; ++nt) {
            const int vrow = nt * 32 + l31;
            const int sw = vrow & 7;
            const short8 vb0 =
                *(const short8*)&Vc[vrow * 64 + ((kh * 4 + h5) ^ sw) * 8];
            const short8 vb1 =
                *(const short8*)&Vc[vrow * 64 + ((kh * 4 + 2 + h5) ^ sw) * 8];
            f32x16& o = nt ? o1 : o0;
            o = __builtin_amdgcn_mfma_f32_32x32x16_bf16(pa0, vb0, o, 0, 0, 0);
            o = __builtin_amdgcn_mfma_f32_32x32x16_bf16(pa1, vb1, o, 0, 0, 0);
        }
    }
    #undef STAGE

    // reduce l across this wave's 32 key-columns (each 32-lane half)
    #pragma unroll
    for (int reg = 0; reg < 16; ++reg) {
        #pragma unroll
        for (int off = 16; off >= 1; off >>= 1)
            l_p[reg] += __shfl_xor(l_p[reg], off, 32);
    }

    __syncthreads();   // all waves done with staging/Ps -> reuse for combine
    float* cb = (float*)smem;             // per rh: 2048 floats (8 KB)
    float* lb = (float*)(smem + 16384);   // [rh][h5][reg] = 64 floats

    if (kh == 1) {
        float* c = cb + rh * 2048;
        #pragma unroll
        for (int reg = 0; reg < 16; ++reg) {
            float2 v = make_float2(o0[reg], o1[reg]);
            *(float2*)&c[reg * 128 + lane * 2] = v;
        }
        if (l31 == 0) {
            #pragma unroll
            for (int reg = 0; reg < 16; ++reg)
                lb[rh * 32 + h5 * 16 + reg] = l_p[reg];
        }
    }
    __syncthreads();
    if (kh == 0) {
        const float* c = cb + rh * 2048;
        #pragma unroll
        for (int reg = 0; reg < 16; ++reg) {
            float2 po = *(const float2*)&c[reg * 128 + lane * 2];
            float lt = l_p[reg] + lb[rh * 32 + h5 * 16 + reg];
            float inv = 1.0f / lt;
            const int r32 = (reg & 3) + 8 * (reg >> 2) + 4 * h5;
            const int s = q0 + rh * 32 + r32;
            u16* dst = ctx + ((size_t)b * S + s) * H + hh * 64;
            dst[l31]      = f2bf((o0[reg] + po.x) * inv);
            dst[32 + l31] = f2bf((o1[reg] + po.y) * inv);
        }
    }
}

// ---------------------------------------------------------------------------
extern "C" void kernel_launch(void* const* d_in, const int* in_sizes, int n_in,
                              void* d_out, int out_size, void* d_ws, size_t ws_size,
                              hipStream_t stream)
{
    const float* hs   = (const float*)d_in[0];
    const float* mask = (const float*)d_in[1];
    const float* Wq   = (const float*)d_in[2];
    const float* bq   = (const float*)d_in[3];
    const float* Wk   = (const float*)d_in[4];
    const float* bk   = (const float*)d_in[5];
    const float* Wv   = (const float*)d_in[6];
    const float* bv   = (const float*)d_in[7];
    const float* Wo   = (const float*)d_in[8];
    const float* bo   = (const float*)d_in[9];
    const float* cosp = (const float*)d_in[10];
    const float* sinp = (const float*)d_in[11];
    float* out = (float*)d_out;

    const size_t per = (size_t)B * NH * S * HD;   // 3,145,728
    u16* ws    = (u16*)d_ws;
    u16* hsb   = ws;                              // bf16 hidden  [BS,H]
    u16* WTqkv = hsb + per;                       // bf16 [2304,768]
    u16* WTo   = WTqkv + (size_t)3 * H * H;       // bf16 [768,768]
    u16* Qb    = WTo + (size_t)H * H;             // bf16 [B,NH,S,HD]
    u16* Kb    = Qb + per;
    u16* VT    = Kb + per;                        // bf16 [B,NH,HD,S]
    u16* ctxb  = VT + per;                        // bf16 [BS,H]

    prep_hs_kernel<<<(BS * H) / 2048, 256, 0, stream>>>(hs, hsb);
    prep_w_kernel<<<dim3(12, 12, 4), 256, 0, stream>>>(
        Wq, Wk, Wv, Wo, WTqkv, WTo);

    gemm_qkv_kernel<<<dim3(BS / 128, 2304 / 128), 256, 0, stream>>>(
        hsb, WTqkv, bq, bk, bv, Qb, Kb, VT);

    rope_kernel<<<dim3(B * NH * S / 4, 2), 256, 0, stream>>>(
        Qb, Kb, cosp, sinp);

    attn_mfma_kernel<<<dim3(S / 64, B * NH), 256, 0, stream>>>(
        Qb, Kb, VT, mask, ctxb);

    gemm_out_kernel<<<dim3(BS / 128, H / 64), 256, 0, stream>>>(
        ctxb, WTo, bo, out);
}

// Round 9
// 195.765 us; speedup vs baseline: 1.1100x; 1.0264x over previous
//
#include <hip/hip_runtime.h>

#define B 2
#define S 2048
#define H 768
#define NH 12
#define HD 64
#define BS (B * S)
#define LOG2E 1.4426950408889634f

typedef unsigned short u16;
typedef short short8 __attribute__((ext_vector_type(8)));
typedef float f32x4 __attribute__((ext_vector_type(4)));
typedef float f32x16 __attribute__((ext_vector_type(16)));

// fp32 -> bf16 round-to-nearest-even
__device__ __forceinline__ u16 f2bf(float f) {
    union { float f; unsigned u; } c; c.f = f;
    unsigned u = c.u + 0x7FFFu + ((c.u >> 16) & 1u);
    return (u16)(u >> 16);
}
__device__ __forceinline__ float bf2f(u16 h) {
    union { unsigned u; float f; } c; c.u = ((unsigned)h) << 16;
    return c.f;
}
__device__ __forceinline__ f32x16 zero16() {
    f32x16 v;
    #pragma unroll
    for (int i = 0; i < 16; ++i) v[i] = 0.f;
    return v;
}

// async global->LDS DMA, 16 B per lane; lds dest = wave-uniform base + lane*16
__device__ __forceinline__ void g2l16(const u16* g, u16* l) {
    __builtin_amdgcn_global_load_lds(
        (const __attribute__((address_space(1))) void*)g,
        (__attribute__((address_space(3))) void*)l, 16, 0, 0);
}

// ---------------------------------------------------------------------------
// Prep 1: hidden_states fp32 -> bf16
// ---------------------------------------------------------------------------
__global__ __launch_bounds__(256) void prep_hs_kernel(
    const float* __restrict__ src, u16* __restrict__ dst)
{
    size_t i = ((size_t)blockIdx.x * 256 + threadIdx.x) * 8;
    float4 a = *(const float4*)(src + i);
    float4 b = *(const float4*)(src + i + 4);
    short8 p;
    p[0] = (short)f2bf(a.x); p[1] = (short)f2bf(a.y);
    p[2] = (short)f2bf(a.z); p[3] = (short)f2bf(a.w);
    p[4] = (short)f2bf(b.x); p[5] = (short)f2bf(b.y);
    p[6] = (short)f2bf(b.z); p[7] = (short)f2bf(b.w);
    *(short8*)(dst + i) = p;
}

// ---------------------------------------------------------------------------
// Prep 2: W [768,768] fp32 -> WT bf16 (WT[n][k] = W[k][n]).
// For z==0 (Wq) / z==1 (Wk): RoPE is folded into the weights. The reference
// indexes cos/sin by HEAD (seq_len_dim=1 quirk), so the rotation is a
// position-independent per-head linear map entirely within this 64-col tile:
//   out[d] = cos[h,d]*w[d] + sgn_d*sin[h,d]*w[p(d)],
//   p(d) = d<32 ? 2d+1 : 2(d-32), sgn_d = d<32 ? -1 : +1.
// z==0 additionally folds the 0.125*log2(e) score scale. Rotated biases are
// written to bqk2[z*H + n] (fp32) by the k0==0 blocks.
// ---------------------------------------------------------------------------
__global__ __launch_bounds__(256) void prep_w_kernel(
    const float* __restrict__ Wq, const float* __restrict__ Wk,
    const float* __restrict__ Wv, const float* __restrict__ Wo,
    const float* __restrict__ bq, const float* __restrict__ bk,
    const float* __restrict__ cosp, const float* __restrict__ sinp,
    u16* __restrict__ WTqkv, u16* __restrict__ WTo,
    float* __restrict__ bqk2)
{
    __shared__ float Lt[64 * 65];
    const int t = threadIdx.x;
    const int z = blockIdx.z;
    const float* W = (z == 0) ? Wq : (z == 1) ? Wk : (z == 2) ? Wv : Wo;
    u16* D = (z == 3) ? WTo : (WTqkv + (size_t)z * H * H);
    const int k0 = blockIdx.x * 64, n0 = blockIdx.y * 64;
    const int head = n0 >> 6;
    const float scl = (z == 0) ? (0.125f * LOG2E) : 1.0f;

    // rotated bias (z<2, once per column-tile)
    if (z < 2 && blockIdx.x == 0 && t < 64) {
        const float* bs = (z == 0) ? bq : bk;
        int d = t;
        int pd = (d < 32) ? (2 * d + 1) : (2 * (d - 32));
        float sv = ((d < 32) ? -1.f : 1.f) * sinp[head * HD + d];
        float cv = cosp[head * HD + d];
        bqk2[z * H + n0 + d] = scl * (cv * bs[n0 + d] + sv * bs[n0 + pd]);
    }

    #pragma unroll
    for (int u = 0; u < 4; ++u) {
        int f = t + u * 256;
        int r = f >> 4, c4 = (f & 15) * 4;
        float4 w = *(const float4*)(W + (size_t)(k0 + r) * H + n0 + c4);
        Lt[r * 65 + c4 + 0] = w.x; Lt[r * 65 + c4 + 1] = w.y;
        Lt[r * 65 + c4 + 2] = w.z; Lt[r * 65 + c4 + 3] = w.w;
    }
    __syncthreads();
    #pragma unroll
    for (int u = 0; u < 4; ++u) {
        int f = t + u * 256;
        int n = f >> 4, k4 = (f & 15) * 4;
        ushort4 p;
        if (z < 2) {
            int pn = (n < 32) ? (2 * n + 1) : (2 * (n - 32));
            float cv = scl * cosp[head * HD + n];
            float sv = scl * ((n < 32) ? -1.f : 1.f) * sinp[head * HD + n];
            p.x = f2bf(cv * Lt[(k4 + 0) * 65 + n] + sv * Lt[(k4 + 0) * 65 + pn]);
            p.y = f2bf(cv * Lt[(k4 + 1) * 65 + n] + sv * Lt[(k4 + 1) * 65 + pn]);
            p.z = f2bf(cv * Lt[(k4 + 2) * 65 + n] + sv * Lt[(k4 + 2) * 65 + pn]);
            p.w = f2bf(cv * Lt[(k4 + 3) * 65 + n] + sv * Lt[(k4 + 3) * 65 + pn]);
        } else {
            p.x = f2bf(Lt[(k4 + 0) * 65 + n]);
            p.y = f2bf(Lt[(k4 + 1) * 65 + n]);
            p.z = f2bf(Lt[(k4 + 2) * 65 + n]);
            p.w = f2bf(Lt[(k4 + 3) * 65 + n]);
        }
        *(ushort4*)(D + (size_t)(n0 + n) * H + k0 + k4) = p;
    }
}

// ---------------------------------------------------------------------------
// Fused QKV GEMM, bf16 MFMA, m97-style global_load_lds staging (2-barrier,
// single-buffered, 32 KB LDS) with source-XOR swizzle for conflict-free
// unpadded LDS. Q/K outputs are FINAL (RoPE+scale folded into weights/bias).
// ---------------------------------------------------------------------------
__global__ __launch_bounds__(256) void gemm_qkv_kernel(
    const u16* __restrict__ A, const u16* __restrict__ BT,
    const float* __restrict__ bqk2, const float* __restrict__ bv,
    u16* __restrict__ Qb, u16* __restrict__ Kb, u16* __restrict__ VT)
{
    __shared__ alignas(16) u16 As[128 * 64];
    __shared__ alignas(16) u16 Bs[128 * 64];

    const int tid  = threadIdx.x;
    const int w    = tid >> 6;
    const int lane = tid & 63;
    const int quad = lane >> 4;
    const int l15  = lane & 15;
    const int wm = (w & 1) * 64, wn = (w >> 1) * 64;
    const int m0 = blockIdx.x * 128;
    const int n0 = blockIdx.y * 128;

    // staging: slot s = u*256+tid; row = s>>3; phys chunk = s&7;
    // logical (source) chunk = (s&7) ^ (row&7)
    int srow[4], slc[4];
    #pragma unroll
    for (int u = 0; u < 4; ++u) {
        int s = u * 256 + tid;
        srow[u] = s >> 3;
        slc[u]  = (s & 7) ^ (srow[u] & 7);
    }

    f32x4 acc[4][4];
    #pragma unroll
    for (int i = 0; i < 4; ++i)
        #pragma unroll
        for (int j = 0; j < 4; ++j) acc[i][j] = (f32x4){0.f, 0.f, 0.f, 0.f};

    for (int k0 = 0; k0 < H; k0 += 64) {
        __syncthreads();   // previous compute done reading LDS
        #pragma unroll
        for (int u = 0; u < 4; ++u) {
            g2l16(A  + (size_t)(m0 + srow[u]) * H + k0 + slc[u] * 8,
                  As + (u * 256 + w * 64) * 8);
            g2l16(BT + (size_t)(n0 + srow[u]) * H + k0 + slc[u] * 8,
                  Bs + (u * 256 + w * 64) * 8);
        }
        __syncthreads();   // drains DMA (vmcnt 0): tiles ready
        #pragma unroll
        for (int kc = 0; kc < 2; ++kc) {      // k = kc*32 + quad*8 + j
            const int ch = kc * 4 + quad;     // logical 16B chunk
            short8 af[4], bf[4];
            #pragma unroll
            for (int mi = 0; mi < 4; ++mi) {
                int row = wm + mi * 16 + l15;
                af[mi] = *(const short8*)&As[row * 64 + (ch ^ (row & 7)) * 8];
            }
            #pragma unroll
            for (int ni = 0; ni < 4; ++ni) {
                int row = wn + ni * 16 + l15;
                bf[ni] = *(const short8*)&Bs[row * 64 + (ch ^ (row & 7)) * 8];
            }
            #pragma unroll
            for (int mi = 0; mi < 4; ++mi)
                #pragma unroll
                for (int ni = 0; ni < 4; ++ni)
                    acc[mi][ni] = __builtin_amdgcn_mfma_f32_16x16x32_bf16(
                        af[mi], bf[ni], acc[mi][ni], 0, 0, 0);
        }
    }

    #pragma unroll
    for (int mi = 0; mi < 4; ++mi) {
        const int mbase = m0 + wm + mi * 16 + quad * 4;
        #pragma unroll
        for (int ni = 0; ni < 4; ++ni) {
            const int col = n0 + wn + ni * 16 + l15;      // 0..2303
            const int which = col / H;
            const int c = col - which * H;
            const int h = c >> 6, d = c & 63;
            if (which == 2) {
                const float bias = bv[c];
                const int b_ = mbase >> 11, s = mbase & (S - 1);
                ushort4 pk;
                pk.x = f2bf(acc[mi][ni][0] + bias);
                pk.y = f2bf(acc[mi][ni][1] + bias);
                pk.z = f2bf(acc[mi][ni][2] + bias);
                pk.w = f2bf(acc[mi][ni][3] + bias);
                *(ushort4*)&VT[(((size_t)b_ * NH + h) * HD + d) * S + s] = pk;
            } else {
                u16* dst = (which == 0) ? Qb : Kb;
                const float bias = bqk2[which * H + c];   // rotated (+scaled)
                #pragma unroll
                for (int r = 0; r < 4; ++r) {
                    int m = mbase + r;
                    int b_ = m >> 11, s = m & (S - 1);
                    dst[(((size_t)b_ * NH + h) * S + s) * HD + d] =
                        f2bf(acc[mi][ni][r] + bias);
                }
            }
        }
    }
}

// ---------------------------------------------------------------------------
// Output projection: out[4096,768] fp32 = ctxb @ WTo^T + bo  (128x64 tile)
// ---------------------------------------------------------------------------
__global__ __launch_bounds__(256) void gemm_out_kernel(
    const u16* __restrict__ A, const u16* __restrict__ BT,
    const float* __restrict__ bo, float* __restrict__ out)
{
    __shared__ alignas(16) u16 As[128 * 72];
    __shared__ alignas(16) u16 Bs[64 * 72];

    const int tid  = threadIdx.x;
    const int w    = tid >> 6;
    const int lane = tid & 63;
    const int quad = lane >> 4;
    const int l15  = lane & 15;
    const int wm = (w & 1) * 64, wn = (w >> 1) * 32;
    const int m0 = blockIdx.x * 128;
    const int n0 = blockIdx.y * 64;
    const int lr = tid >> 3, lc8 = (tid & 7) * 8;

    f32x4 acc[4][2];
    #pragma unroll
    for (int i = 0; i < 4; ++i)
        #pragma unroll
        for (int j = 0; j < 2; ++j) acc[i][j] = (f32x4){0.f, 0.f, 0.f, 0.f};

    short8 pa[2], pa2[2], pb[2];
    #pragma unroll
    for (int u = 0; u < 2; ++u) {
        pa[u]  = *(const short8*)(A  + (size_t)(m0 + lr + u * 32) * H + lc8);
        pa2[u] = *(const short8*)(A  + (size_t)(m0 + lr + 64 + u * 32) * H + lc8);
        pb[u]  = *(const short8*)(BT + (size_t)(n0 + lr + u * 32) * H + lc8);
    }

    for (int k0 = 0; k0 < H; k0 += 64) {
        __syncthreads();
        #pragma unroll
        for (int u = 0; u < 2; ++u) {
            *(short8*)&As[(lr + u * 32) * 72 + lc8] = pa[u];
            *(short8*)&As[(lr + 64 + u * 32) * 72 + lc8] = pa2[u];
            *(short8*)&Bs[(lr + u * 32) * 72 + lc8] = pb[u];
        }
        if (k0 + 64 < H) {
            #pragma unroll
            for (int u = 0; u < 2; ++u) {
                pa[u]  = *(const short8*)(A  + (size_t)(m0 + lr + u * 32) * H + k0 + 64 + lc8);
                pa2[u] = *(const short8*)(A  + (size_t)(m0 + lr + 64 + u * 32) * H + k0 + 64 + lc8);
                pb[u]  = *(const short8*)(BT + (size_t)(n0 + lr + u * 32) * H + k0 + 64 + lc8);
            }
        }
        __syncthreads();
        #pragma unroll
        for (int kc = 0; kc < 64; kc += 32) {
            short8 af[4], bf[2];
            #pragma unroll
            for (int mi = 0; mi < 4; ++mi)
                af[mi] = *(const short8*)&As[(wm + mi * 16 + l15) * 72 + kc + quad * 8];
            #pragma unroll
            for (int ni = 0; ni < 2; ++ni)
                bf[ni] = *(const short8*)&Bs[(wn + ni * 16 + l15) * 72 + kc + quad * 8];
            #pragma unroll
            for (int mi = 0; mi < 4; ++mi)
                #pragma unroll
                for (int ni = 0; ni < 2; ++ni)
                    acc[mi][ni] = __builtin_amdgcn_mfma_f32_16x16x32_bf16(
                        af[mi], bf[ni], acc[mi][ni], 0, 0, 0);
        }
    }

    #pragma unroll
    for (int mi = 0; mi < 4; ++mi) {
        const int mbase = m0 + wm + mi * 16 + quad * 4;
        #pragma unroll
        for (int ni = 0; ni < 2; ++ni) {
            const int col = n0 + wn + ni * 16 + l15;
            const float bias = bo[col];
            #pragma unroll
            for (int r = 0; r < 4; ++r)
                out[(size_t)(mbase + r) * H + col] = acc[mi][ni][r] + bias;
        }
    }
}

// ---------------------------------------------------------------------------
// Flash attention, bf16 32x32x16 MFMA, exp2 no-max softmax, DMA-dbuf K/V.
// (unchanged from round 8)
// ---------------------------------------------------------------------------
__global__ __launch_bounds__(256) void attn_mfma_kernel(
    const u16* __restrict__ Q, const u16* __restrict__ K,
    const u16* __restrict__ VT, const float* __restrict__ mask,
    u16* __restrict__ ctx)
{
    __shared__ alignas(16) u16 smem[21504];
    u16* const Kbase = smem;
    u16* const Vbase = smem + 8192;
    u16* const Psw   = smem + 16384 + (threadIdx.x >> 6) * 1280;

    const int tid  = threadIdx.x;
    const int w    = tid >> 6;
    const int lane = tid & 63;
    const int l31  = lane & 31;
    const int h5   = lane >> 5;
    const int rh   = w & 1;   // row-half
    const int kh   = w >> 1;  // key-half
    const int bn = blockIdx.y, b = bn / NH, hh = bn % NH;
    const int q0 = blockIdx.x * 64;
    const int NT = S / 64;

    short8 qa[4];
    {
        const u16* Qp = Q + ((size_t)bn * S + q0 + rh * 32 + l31) * HD + h5 * 8;
        #pragma unroll
        for (int kc = 0; kc < 4; ++kc)
            qa[kc] = *(const short8*)(Qp + kc * 16);
    }

    const u16* Kg = K + (size_t)bn * S * HD;
    const u16* Vg = VT + (size_t)bn * HD * S;
    const float* mrow = mask + (size_t)b * S;

    int srow[2], slc[2];
    #pragma unroll
    for (int u = 0; u < 2; ++u) {
        int s = u * 256 + tid;
        srow[u] = s >> 3;
        slc[u]  = (s & 7) ^ (srow[u] & 7);
    }

    #define STAGE(JT, NB)                                                     \
        _Pragma("unroll")                                                     \
        for (int u = 0; u < 2; ++u) {                                         \
            g2l16(Kg + (size_t)((JT) * 64 + srow[u]) * HD + slc[u] * 8,       \
                  Kbase + (NB) * 4096 + (u * 256 + w * 64) * 8);              \
            g2l16(Vg + (size_t)srow[u] * S + (JT) * 64 + slc[u] * 8,          \
                  Vbase + (NB) * 4096 + (u * 256 + w * 64) * 8);              \
        }

    STAGE(0, 0)

    f32x16 o0 = zero16(), o1 = zero16();
    float l_p[16];
    #pragma unroll
    for (int i = 0; i < 16; ++i) l_p[i] = 0.f;

    for (int jt = 0; jt < NT; ++jt) {
        const int cur = jt & 1;
        const float mv = mrow[jt * 64 + kh * 32 + l31];
        __syncthreads();
        if (jt + 1 < NT) { STAGE(jt + 1, cur ^ 1) }

        const u16* Kc = Kbase + cur * 4096;
        const u16* Vc = Vbase + cur * 4096;

        f32x16 sc = zero16();
        {
            const int krow = kh * 32 + l31;
            const int sw = krow & 7;
            #pragma unroll
            for (int kc = 0; kc < 4; ++kc) {
                const short8 kb =
                    *(const short8*)&Kc[krow * 64 + ((kc * 2 + h5) ^ sw) * 8];
                sc = __builtin_amdgcn_mfma_f32_32x32x16_bf16(qa[kc], kb, sc, 0, 0, 0);
            }
        }

        const float mt = (1.0f - mv) * (-10000.0f * LOG2E);
        #pragma unroll
        for (int reg = 0; reg < 16; ++reg) {
            float p = __builtin_amdgcn_exp2f(sc[reg] + mt);
            l_p[reg] += p;
            const int r32 = (reg & 3) + 8 * (reg >> 2) + 4 * h5;
            Psw[r32 * 40 + l31] = f2bf(p);
        }

        asm volatile("s_waitcnt lgkmcnt(0)" ::: "memory");

        const short8 pa0 = *(const short8*)&Psw[l31 * 40 + h5 * 8];
        const short8 pa1 = *(const short8*)&Psw[l31 * 40 + 16 + h5 * 8];

        #pragma unroll
        for (int nt = 0; nt < 2; ++nt) {
            const int vrow = nt * 32 + l31;
            const int sw = vrow & 7;
            const short8 vb0 =
                *(const short8*)&Vc[vrow * 64 + ((kh * 4 + h5) ^ sw) * 8];
            const short8 vb1 =
                *(const short8*)&Vc[vrow * 64 + ((kh * 4 + 2 + h5) ^ sw) * 8];
            f32x16& o = nt ? o1 : o0;
            o = __builtin_amdgcn_mfma_f32_32x32x16_bf16(pa0, vb0, o, 0, 0, 0);
            o = __builtin_amdgcn_mfma_f32_32x32x16_bf16(pa1, vb1, o, 0, 0, 0);
        }
    }
    #undef STAGE

    #pragma unroll
    for (int reg = 0; reg < 16; ++reg) {
        #pragma unroll
        for (int off = 16; off >= 1; off >>= 1)
            l_p[reg] += __shfl_xor(l_p[reg], off, 32);
    }

    __syncthreads();
    float* cb = (float*)smem;
    float* lb = (float*)(smem + 16384);

    if (kh == 1) {
        float* c = cb + rh * 2048;
        #pragma unroll
        for (int reg = 0; reg < 16; ++reg) {
            float2 v = make_float2(o0[reg], o1[reg]);
            *(float2*)&c[reg * 128 + lane * 2] = v;
        }
        if (l31 == 0) {
            #pragma unroll
            for (int reg = 0; reg < 16; ++reg)
                lb[rh * 32 + h5 * 16 + reg] = l_p[reg];
        }
    }
    __syncthreads();
    if (kh == 0) {
        const float* c = cb + rh * 2048;
        #pragma unroll
        for (int reg = 0; reg < 16; ++reg) {
            float2 po = *(const float2*)&c[reg * 128 + lane * 2];
            float lt = l_p[reg] + lb[rh * 32 + h5 * 16 + reg];
            float inv = 1.0f / lt;
            const int r32 = (reg & 3) + 8 * (reg >> 2) + 4 * h5;
            const int s = q0 + rh * 32 + r32;
            u16* dst = ctx + ((size_t)b * S + s) * H + hh * 64;
            dst[l31]      = f2bf((o0[reg] + po.x) * inv);
            dst[32 + l31] = f2bf((o1[reg] + po.y) * inv);
        }
    }
}

// ---------------------------------------------------------------------------
extern "C" void kernel_launch(void* const* d_in, const int* in_sizes, int n_in,
                              void* d_out, int out_size, void* d_ws, size_t ws_size,
                              hipStream_t stream)
{
    const float* hs   = (const float*)d_in[0];
    const float* mask = (const float*)d_in[1];
    const float* Wq   = (const float*)d_in[2];
    const float* bq   = (const float*)d_in[3];
    const float* Wk   = (const float*)d_in[4];
    const float* bk   = (const float*)d_in[5];
    const float* Wv   = (const float*)d_in[6];
    const float* bv   = (const float*)d_in[7];
    const float* Wo   = (const float*)d_in[8];
    const float* bo   = (const float*)d_in[9];
    const float* cosp = (const float*)d_in[10];
    const float* sinp = (const float*)d_in[11];
    float* out = (float*)d_out;

    const size_t per = (size_t)B * NH * S * HD;   // 3,145,728
    u16* ws    = (u16*)d_ws;
    u16* hsb   = ws;                              // bf16 hidden  [BS,H]
    u16* WTqkv = hsb + per;                       // bf16 [2304,768] (Q/K rotated)
    u16* WTo   = WTqkv + (size_t)3 * H * H;       // bf16 [768,768]
    u16* Qb    = WTo + (size_t)H * H;             // bf16 [B,NH,S,HD] final
    u16* Kb    = Qb + per;                        // bf16 final
    u16* VT    = Kb + per;                        // bf16 [B,NH,HD,S]
    u16* ctxb  = VT + per;                        // bf16 [BS,H]
    float* bqk2 = (float*)(ctxb + per);           // rotated biases [2*H]

    prep_hs_kernel<<<(BS * H) / 2048, 256, 0, stream>>>(hs, hsb);
    prep_w_kernel<<<dim3(12, 12, 4), 256, 0, stream>>>(
        Wq, Wk, Wv, Wo, bq, bk, cosp, sinp, WTqkv, WTo, bqk2);

    gemm_qkv_kernel<<<dim3(BS / 128, 2304 / 128), 256, 0, stream>>>(
        hsb, WTqkv, bqk2, bv, Qb, Kb, VT);

    attn_mfma_kernel<<<dim3(S / 64, B * NH), 256, 0, stream>>>(
        Qb, Kb, VT, mask, ctxb);

    gemm_out_kernel<<<dim3(BS / 128, H / 64), 256, 0, stream>>>(
        ctxb, WTo, bo, out);
}

// Round 10
// 191.269 us; speedup vs baseline: 1.1361x; 1.0235x over previous
//
#include <hip/hip_runtime.h>

#define B 2
#define S 2048
#define H 768
#define NH 12
#define HD 64
#define BS (B * S)
#define LOG2E 1.4426950408889634f

typedef unsigned short u16;
typedef short short8 __attribute__((ext_vector_type(8)));
typedef float f32x4 __attribute__((ext_vector_type(4)));
typedef float f32x16 __attribute__((ext_vector_type(16)));

// fp32 -> bf16 round-to-nearest-even
__device__ __forceinline__ u16 f2bf(float f) {
    union { float f; unsigned u; } c; c.f = f;
    unsigned u = c.u + 0x7FFFu + ((c.u >> 16) & 1u);
    return (u16)(u >> 16);
}
__device__ __forceinline__ float bf2f(u16 h) {
    union { unsigned u; float f; } c; c.u = ((unsigned)h) << 16;
    return c.f;
}
__device__ __forceinline__ f32x16 zero16() {
    f32x16 v;
    #pragma unroll
    for (int i = 0; i < 16; ++i) v[i] = 0.f;
    return v;
}

// async global->LDS DMA, 16 B per lane; lds dest = wave-uniform base + lane*16
__device__ __forceinline__ void g2l16(const u16* g, u16* l) {
    __builtin_amdgcn_global_load_lds(
        (const __attribute__((address_space(1))) void*)g,
        (__attribute__((address_space(3))) void*)l, 16, 0, 0);
}

// ---------------------------------------------------------------------------
// Merged prep: blocks [0,576) transpose+convert weights (RoPE folded into
// Wq/Wk per the reference's head-indexed-table quirk; Q also folds
// 0.125*log2e); blocks [576,2112) convert hidden_states fp32->bf16.
// ---------------------------------------------------------------------------
__global__ __launch_bounds__(256) void prep_kernel(
    const float* __restrict__ hs,
    const float* __restrict__ Wq, const float* __restrict__ Wk,
    const float* __restrict__ Wv, const float* __restrict__ Wo,
    const float* __restrict__ bq, const float* __restrict__ bk,
    const float* __restrict__ cosp, const float* __restrict__ sinp,
    u16* __restrict__ hsb, u16* __restrict__ WTqkv, u16* __restrict__ WTo,
    float* __restrict__ bqk2)
{
    __shared__ float Lt[64 * 65];
    const int bid = blockIdx.x;
    const int t = threadIdx.x;

    if (bid >= 576) {                       // ---- hidden_states convert ----
        size_t i = ((size_t)(bid - 576) * 256 + t) * 8;
        float4 a = *(const float4*)(hs + i);
        float4 b = *(const float4*)(hs + i + 4);
        short8 p;
        p[0] = (short)f2bf(a.x); p[1] = (short)f2bf(a.y);
        p[2] = (short)f2bf(a.z); p[3] = (short)f2bf(a.w);
        p[4] = (short)f2bf(b.x); p[5] = (short)f2bf(b.y);
        p[6] = (short)f2bf(b.z); p[7] = (short)f2bf(b.w);
        *(short8*)(hsb + i) = p;
        return;
    }

    // ---- weight transpose (+RoPE fold for z<2) ----
    const int z   = bid / 144;
    const int rem = bid - z * 144;
    const int k0 = (rem / 12) * 64, n0 = (rem % 12) * 64;
    const float* W = (z == 0) ? Wq : (z == 1) ? Wk : (z == 2) ? Wv : Wo;
    u16* D = (z == 3) ? WTo : (WTqkv + (size_t)z * H * H);
    const int head = n0 >> 6;
    const float scl = (z == 0) ? (0.125f * LOG2E) : 1.0f;

    if (z < 2 && rem / 12 == 0 && t < 64) {   // rotated bias, once per col-tile
        const float* bs = (z == 0) ? bq : bk;
        int d = t;
        int pd = (d < 32) ? (2 * d + 1) : (2 * (d - 32));
        float sv = ((d < 32) ? -1.f : 1.f) * sinp[head * HD + d];
        float cv = cosp[head * HD + d];
        bqk2[z * H + n0 + d] = scl * (cv * bs[n0 + d] + sv * bs[n0 + pd]);
    }

    #pragma unroll
    for (int u = 0; u < 4; ++u) {
        int f = t + u * 256;
        int r = f >> 4, c4 = (f & 15) * 4;
        float4 w = *(const float4*)(W + (size_t)(k0 + r) * H + n0 + c4);
        Lt[r * 65 + c4 + 0] = w.x; Lt[r * 65 + c4 + 1] = w.y;
        Lt[r * 65 + c4 + 2] = w.z; Lt[r * 65 + c4 + 3] = w.w;
    }
    __syncthreads();
    #pragma unroll
    for (int u = 0; u < 4; ++u) {
        int f = t + u * 256;
        int n = f >> 4, k4 = (f & 15) * 4;
        ushort4 p;
        if (z < 2) {
            int pn = (n < 32) ? (2 * n + 1) : (2 * (n - 32));
            float cv = scl * cosp[head * HD + n];
            float sv = scl * ((n < 32) ? -1.f : 1.f) * sinp[head * HD + n];
            p.x = f2bf(cv * Lt[(k4 + 0) * 65 + n] + sv * Lt[(k4 + 0) * 65 + pn]);
            p.y = f2bf(cv * Lt[(k4 + 1) * 65 + n] + sv * Lt[(k4 + 1) * 65 + pn]);
            p.z = f2bf(cv * Lt[(k4 + 2) * 65 + n] + sv * Lt[(k4 + 2) * 65 + pn]);
            p.w = f2bf(cv * Lt[(k4 + 3) * 65 + n] + sv * Lt[(k4 + 3) * 65 + pn]);
        } else {
            p.x = f2bf(Lt[(k4 + 0) * 65 + n]);
            p.y = f2bf(Lt[(k4 + 1) * 65 + n]);
            p.z = f2bf(Lt[(k4 + 2) * 65 + n]);
            p.w = f2bf(Lt[(k4 + 3) * 65 + n]);
        }
        *(ushort4*)(D + (size_t)(n0 + n) * H + k0 + k4) = p;
    }
}

// ---------------------------------------------------------------------------
// Fused QKV GEMM, bf16 MFMA, DMA DOUBLE-buffered staging: ONE barrier per
// K-slab (attn-kernel structure). XOR-swizzled unpadded LDS. Q/K outputs
// final (RoPE+scale folded into weights/bias).
// ---------------------------------------------------------------------------
__global__ __launch_bounds__(256) void gemm_qkv_kernel(
    const u16* __restrict__ A, const u16* __restrict__ BT,
    const float* __restrict__ bqk2, const float* __restrict__ bv,
    u16* __restrict__ Qb, u16* __restrict__ Kb, u16* __restrict__ VT)
{
    __shared__ alignas(16) u16 Abuf[2][128 * 64];
    __shared__ alignas(16) u16 Bbuf[2][128 * 64];

    const int tid  = threadIdx.x;
    const int w    = tid >> 6;
    const int lane = tid & 63;
    const int quad = lane >> 4;
    const int l15  = lane & 15;
    const int wm = (w & 1) * 64, wn = (w >> 1) * 64;
    const int m0 = blockIdx.x * 128;
    const int n0 = blockIdx.y * 128;
    const int NK = H / 64;   // 12

    int srow[4], slc[4];
    #pragma unroll
    for (int u = 0; u < 4; ++u) {
        int s = u * 256 + tid;
        srow[u] = s >> 3;
        slc[u]  = (s & 7) ^ (srow[u] & 7);
    }

    #define QSTAGE(IT, NB)                                                    \
        _Pragma("unroll")                                                     \
        for (int u = 0; u < 4; ++u) {                                         \
            g2l16(A  + (size_t)(m0 + srow[u]) * H + (IT) * 64 + slc[u] * 8,   \
                  &Abuf[NB][(u * 256 + w * 64) * 8]);                         \
            g2l16(BT + (size_t)(n0 + srow[u]) * H + (IT) * 64 + slc[u] * 8,   \
                  &Bbuf[NB][(u * 256 + w * 64) * 8]);                         \
        }

    QSTAGE(0, 0)

    f32x4 acc[4][4];
    #pragma unroll
    for (int i = 0; i < 4; ++i)
        #pragma unroll
        for (int j = 0; j < 4; ++j) acc[i][j] = (f32x4){0.f, 0.f, 0.f, 0.f};

    for (int it = 0; it < NK; ++it) {
        const int cur = it & 1;
        __syncthreads();                       // drains DMA for buffer cur
        if (it + 1 < NK) { QSTAGE(it + 1, cur ^ 1) }

        const u16* Ac = Abuf[cur];
        const u16* Bc = Bbuf[cur];
        #pragma unroll
        for (int kc = 0; kc < 2; ++kc) {
            const int ch = kc * 4 + quad;
            short8 af[4], bf[4];
            #pragma unroll
            for (int mi = 0; mi < 4; ++mi) {
                int row = wm + mi * 16 + l15;
                af[mi] = *(const short8*)&Ac[row * 64 + (ch ^ (row & 7)) * 8];
            }
            #pragma unroll
            for (int ni = 0; ni < 4; ++ni) {
                int row = wn + ni * 16 + l15;
                bf[ni] = *(const short8*)&Bc[row * 64 + (ch ^ (row & 7)) * 8];
            }
            #pragma unroll
            for (int mi = 0; mi < 4; ++mi)
                #pragma unroll
                for (int ni = 0; ni < 4; ++ni)
                    acc[mi][ni] = __builtin_amdgcn_mfma_f32_16x16x32_bf16(
                        af[mi], bf[ni], acc[mi][ni], 0, 0, 0);
        }
    }
    #undef QSTAGE

    #pragma unroll
    for (int mi = 0; mi < 4; ++mi) {
        const int mbase = m0 + wm + mi * 16 + quad * 4;
        #pragma unroll
        for (int ni = 0; ni < 4; ++ni) {
            const int col = n0 + wn + ni * 16 + l15;      // 0..2303
            const int which = col / H;
            const int c = col - which * H;
            const int h = c >> 6, d = c & 63;
            if (which == 2) {
                const float bias = bv[c];
                const int b_ = mbase >> 11, s = mbase & (S - 1);
                ushort4 pk;
                pk.x = f2bf(acc[mi][ni][0] + bias);
                pk.y = f2bf(acc[mi][ni][1] + bias);
                pk.z = f2bf(acc[mi][ni][2] + bias);
                pk.w = f2bf(acc[mi][ni][3] + bias);
                *(ushort4*)&VT[(((size_t)b_ * NH + h) * HD + d) * S + s] = pk;
            } else {
                u16* dst = (which == 0) ? Qb : Kb;
                const float bias = bqk2[which * H + c];   // rotated (+scaled)
                #pragma unroll
                for (int r = 0; r < 4; ++r) {
                    int m = mbase + r;
                    int b_ = m >> 11, s = m & (S - 1);
                    dst[(((size_t)b_ * NH + h) * S + s) * HD + d] =
                        f2bf(acc[mi][ni][r] + bias);
                }
            }
        }
    }
}

// ---------------------------------------------------------------------------
// Output projection: out[4096,768] fp32 = ctxb @ WTo^T + bo. 128x64 tile,
// DMA double-buffered staging (one barrier per K-slab), XOR-swizzled LDS.
// ---------------------------------------------------------------------------
__global__ __launch_bounds__(256) void gemm_out_kernel(
    const u16* __restrict__ A, const u16* __restrict__ BT,
    const float* __restrict__ bo, float* __restrict__ out)
{
    __shared__ alignas(16) u16 Abuf[2][128 * 64];
    __shared__ alignas(16) u16 Bbuf[2][64 * 64];

    const int tid  = threadIdx.x;
    const int w    = tid >> 6;
    const int lane = tid & 63;
    const int quad = lane >> 4;
    const int l15  = lane & 15;
    const int wm = (w & 1) * 64, wn = (w >> 1) * 32;
    const int m0 = blockIdx.x * 128;
    const int n0 = blockIdx.y * 64;
    const int NK = H / 64;

    int srow[4], slc[4];
    #pragma unroll
    for (int u = 0; u < 4; ++u) {
        int s = u * 256 + tid;
        srow[u] = s >> 3;
        slc[u]  = (s & 7) ^ (srow[u] & 7);
    }

    #define OSTAGE(IT, NB)                                                    \
        _Pragma("unroll")                                                     \
        for (int u = 0; u < 4; ++u)                                           \
            g2l16(A + (size_t)(m0 + srow[u]) * H + (IT) * 64 + slc[u] * 8,    \
                  &Abuf[NB][(u * 256 + w * 64) * 8]);                         \
        _Pragma("unroll")                                                     \
        for (int u = 0; u < 2; ++u)                                           \
            g2l16(BT + (size_t)(n0 + srow[u]) * H + (IT) * 64 + slc[u] * 8,   \
                  &Bbuf[NB][(u * 256 + w * 64) * 8]);

    OSTAGE(0, 0)

    f32x4 acc[4][2];
    #pragma unroll
    for (int i = 0; i < 4; ++i)
        #pragma unroll
        for (int j = 0; j < 2; ++j) acc[i][j] = (f32x4){0.f, 0.f, 0.f, 0.f};

    for (int it = 0; it < NK; ++it) {
        const int cur = it & 1;
        __syncthreads();
        if (it + 1 < NK) { OSTAGE(it + 1, cur ^ 1) }

        const u16* Ac = Abuf[cur];
        const u16* Bc = Bbuf[cur];
        #pragma unroll
        for (int kc = 0; kc < 2; ++kc) {
            const int ch = kc * 4 + quad;
            short8 af[4], bf[2];
            #pragma unroll
            for (int mi = 0; mi < 4; ++mi) {
                int row = wm + mi * 16 + l15;
                af[mi] = *(const short8*)&Ac[row * 64 + (ch ^ (row & 7)) * 8];
            }
            #pragma unroll
            for (int ni = 0; ni < 2; ++ni) {
                int row = wn + ni * 16 + l15;
                bf[ni] = *(const short8*)&Bc[row * 64 + (ch ^ (row & 7)) * 8];
            }
            #pragma unroll
            for (int mi = 0; mi < 4; ++mi)
                #pragma unroll
                for (int ni = 0; ni < 2; ++ni)
                    acc[mi][ni] = __builtin_amdgcn_mfma_f32_16x16x32_bf16(
                        af[mi], bf[ni], acc[mi][ni], 0, 0, 0);
        }
    }
    #undef OSTAGE

    #pragma unroll
    for (int mi = 0; mi < 4; ++mi) {
        const int mbase = m0 + wm + mi * 16 + quad * 4;
        #pragma unroll
        for (int ni = 0; ni < 2; ++ni) {
            const int col = n0 + wn + ni * 16 + l15;
            const float bias = bo[col];
            #pragma unroll
            for (int r = 0; r < 4; ++r)
                out[(size_t)(mbase + r) * H + col] = acc[mi][ni][r] + bias;
        }
    }
}

// ---------------------------------------------------------------------------
// Flash attention, bf16 32x32x16 MFMA, exp2 no-max softmax, DMA-dbuf K/V.
// (unchanged from rounds 8/9)
// ---------------------------------------------------------------------------
__global__ __launch_bounds__(256) void attn_mfma_kernel(
    const u16* __restrict__ Q, const u16* __restrict__ K,
    const u16* __restrict__ VT, const float* __restrict__ mask,
    u16* __restrict__ ctx)
{
    __shared__ alignas(16) u16 smem[21504];
    u16* const Kbase = smem;
    u16* const Vbase = smem + 8192;
    u16* const Psw   = smem + 16384 + (threadIdx.x >> 6) * 1280;

    const int tid  = threadIdx.x;
    const int w    = tid >> 6;
    const int lane = tid & 63;
    const int l31  = lane & 31;
    const int h5   = lane >> 5;
    const int rh   = w & 1;   // row-half
    const int kh   = w >> 1;  // key-half
    const int bn = blockIdx.y, b = bn / NH, hh = bn % NH;
    const int q0 = blockIdx.x * 64;
    const int NT = S / 64;

    short8 qa[4];
    {
        const u16* Qp = Q + ((size_t)bn * S + q0 + rh * 32 + l31) * HD + h5 * 8;
        #pragma unroll
        for (int kc = 0; kc < 4; ++kc)
            qa[kc] = *(const short8*)(Qp + kc * 16);
    }

    const u16* Kg = K + (size_t)bn * S * HD;
    const u16* Vg = VT + (size_t)bn * HD * S;
    const float* mrow = mask + (size_t)b * S;

    int srow[2], slc[2];
    #pragma unroll
    for (int u = 0; u < 2; ++u) {
        int s = u * 256 + tid;
        srow[u] = s >> 3;
        slc[u]  = (s & 7) ^ (srow[u] & 7);
    }

    #define STAGE(JT, NB)                                                     \
        _Pragma("unroll")                                                     \
        for (int u = 0; u < 2; ++u) {                                         \
            g2l16(Kg + (size_t)((JT) * 64 + srow[u]) * HD + slc[u] * 8,       \
                  Kbase + (NB) * 4096 + (u * 256 + w * 64) * 8);              \
            g2l16(Vg + (size_t)srow[u] * S + (JT) * 64 + slc[u] * 8,          \
                  Vbase + (NB) * 4096 + (u * 256 + w * 64) * 8);              \
        }

    STAGE(0, 0)

    f32x16 o0 = zero16(), o1 = zero16();
    float l_p[16];
    #pragma unroll
    for (int i = 0; i < 16; ++i) l_p[i] = 0.f;

    for (int jt = 0; jt < NT; ++jt) {
        const int cur = jt & 1;
        const float mv = mrow[jt * 64 + kh * 32 + l31];
        __syncthreads();
        if (jt + 1 < NT) { STAGE(jt + 1, cur ^ 1) }

        const u16* Kc = Kbase + cur * 4096;
        const u16* Vc = Vbase + cur * 4096;

        f32x16 sc = zero16();
        {
            const int krow = kh * 32 + l31;
            const int sw = krow & 7;
            #pragma unroll
            for (int kc = 0; kc < 4; ++kc) {
                const short8 kb =
                    *(const short8*)&Kc[krow * 64 + ((kc * 2 + h5) ^ sw) * 8];
                sc = __builtin_amdgcn_mfma_f32_32x32x16_bf16(qa[kc], kb, sc, 0, 0, 0);
            }
        }

        const float mt = (1.0f - mv) * (-10000.0f * LOG2E);
        #pragma unroll
        for (int reg = 0; reg < 16; ++reg) {
            float p = __builtin_amdgcn_exp2f(sc[reg] + mt);
            l_p[reg] += p;
            const int r32 = (reg & 3) + 8 * (reg >> 2) + 4 * h5;
            Psw[r32 * 40 + l31] = f2bf(p);
        }

        asm volatile("s_waitcnt lgkmcnt(0)" ::: "memory");

        const short8 pa0 = *(const short8*)&Psw[l31 * 40 + h5 * 8];
        const short8 pa1 = *(const short8*)&Psw[l31 * 40 + 16 + h5 * 8];

        #pragma unroll
        for (int nt = 0; nt < 2; ++nt) {
            const int vrow = nt * 32 + l31;
            const int sw = vrow & 7;
            const short8 vb0 =
                *(const short8*)&Vc[vrow * 64 + ((kh * 4 + h5) ^ sw) * 8];
            const short8 vb1 =
                *(const short8*)&Vc[vrow * 64 + ((kh * 4 + 2 + h5) ^ sw) * 8];
            f32x16& o = nt ? o1 : o0;
            o = __builtin_amdgcn_mfma_f32_32x32x16_bf16(pa0, vb0, o, 0, 0, 0);
            o = __builtin_amdgcn_mfma_f32_32x32x16_bf16(pa1, vb1, o, 0, 0, 0);
        }
    }
    #undef STAGE

    #pragma unroll
    for (int reg = 0; reg < 16; ++reg) {
        #pragma unroll
        for (int off = 16; off >= 1; off >>= 1)
            l_p[reg] += __shfl_xor(l_p[reg], off, 32);
    }

    __syncthreads();
    float* cb = (float*)smem;
    float* lb = (float*)(smem + 16384);

    if (kh == 1) {
        float* c = cb + rh * 2048;
        #pragma unroll
        for (int reg = 0; reg < 16; ++reg) {
            float2 v = make_float2(o0[reg], o1[reg]);
            *(float2*)&c[reg * 128 + lane * 2] = v;
        }
        if (l31 == 0) {
            #pragma unroll
            for (int reg = 0; reg < 16; ++reg)
                lb[rh * 32 + h5 * 16 + reg] = l_p[reg];
        }
    }
    __syncthreads();
    if (kh == 0) {
        const float* c = cb + rh * 2048;
        #pragma unroll
        for (int reg = 0; reg < 16; ++reg) {
            float2 po = *(const float2*)&c[reg * 128 + lane * 2];
            float lt = l_p[reg] + lb[rh * 32 + h5 * 16 + reg];
            float inv = 1.0f / lt;
            const int r32 = (reg & 3) + 8 * (reg >> 2) + 4 * h5;
            const int s = q0 + rh * 32 + r32;
            u16* dst = ctx + ((size_t)b * S + s) * H + hh * 64;
            dst[l31]      = f2bf((o0[reg] + po.x) * inv);
            dst[32 + l31] = f2bf((o1[reg] + po.y) * inv);
        }
    }
}

// ---------------------------------------------------------------------------
extern "C" void kernel_launch(void* const* d_in, const int* in_sizes, int n_in,
                              void* d_out, int out_size, void* d_ws, size_t ws_size,
                              hipStream_t stream)
{
    const float* hs   = (const float*)d_in[0];
    const float* mask = (const float*)d_in[1];
    const float* Wq   = (const float*)d_in[2];
    const float* bq   = (const float*)d_in[3];
    const float* Wk   = (const float*)d_in[4];
    const float* bk   = (const float*)d_in[5];
    const float* Wv   = (const float*)d_in[6];
    const float* bv   = (const float*)d_in[7];
    const float* Wo   = (const float*)d_in[8];
    const float* bo   = (const float*)d_in[9];
    const float* cosp = (const float*)d_in[10];
    const float* sinp = (const float*)d_in[11];
    float* out = (float*)d_out;

    const size_t per = (size_t)B * NH * S * HD;   // 3,145,728
    u16* ws    = (u16*)d_ws;
    u16* hsb   = ws;                              // bf16 hidden  [BS,H]
    u16* WTqkv = hsb + per;                       // bf16 [2304,768] (Q/K rotated)
    u16* WTo   = WTqkv + (size_t)3 * H * H;       // bf16 [768,768]
    u16* Qb    = WTo + (size_t)H * H;             // bf16 [B,NH,S,HD] final
    u16* Kb    = Qb + per;                        // bf16 final
    u16* VT    = Kb + per;                        // bf16 [B,NH,HD,S]
    u16* ctxb  = VT + per;                        // bf16 [BS,H]
    float* bqk2 = (float*)(ctxb + per);           // rotated biases [2*H]

    prep_kernel<<<576 + (BS * H) / 2048, 256, 0, stream>>>(
        hs, Wq, Wk, Wv, Wo, bq, bk, cosp, sinp, hsb, WTqkv, WTo, bqk2);

    gemm_qkv_kernel<<<dim3(BS / 128, 2304 / 128), 256, 0, stream>>>(
        hsb, WTqkv, bqk2, bv, Qb, Kb, VT);

    attn_mfma_kernel<<<dim3(S / 64, B * NH), 256, 0, stream>>>(
        Qb, Kb, VT, mask, ctxb);

    gemm_out_kernel<<<dim3(BS / 128, H / 64), 256, 0, stream>>>(
        ctxb, WTo, bo, out);
}